// Round 1
// baseline (361.591 us; speedup 1.0000x reference)
//
#include <hip/hip_runtime.h>
#include <hip/hip_bf16.h>

// Problem constants
constexpr int BATCH = 2, SEQ = 2048, HDIM = 1024, NHEADS = 16, HEADD = 64;
constexpr int MROWS = BATCH * SEQ;            // 4096
constexpr long MASK_N = (long)BATCH * SEQ * SEQ; // 8388608

typedef short short8 __attribute__((ext_vector_type(8)));
typedef float f32x4  __attribute__((ext_vector_type(4)));

static __device__ __forceinline__ short f2bf(float f) {
    __hip_bfloat16 h = __float2bfloat16(f);
    return *reinterpret_cast<short*>(&h);
}

static __device__ __forceinline__ void gload_lds16(const void* g, void* l) {
    __builtin_amdgcn_global_load_lds(
        (const __attribute__((address_space(1))) unsigned int*)g,
        (__attribute__((address_space(3))) unsigned int*)l, 16, 0, 0);
}

// ---------------- conversion: f32 -> bf16 (vectorized x4) ----------------
__global__ void f32_to_bf16_kernel(const float* __restrict__ in,
                                   short* __restrict__ out, int n4) {
    int i = blockIdx.x * blockDim.x + threadIdx.x;
    const int stride = gridDim.x * blockDim.x;
    for (; i < n4; i += stride) {
        const float4 v = reinterpret_cast<const float4*>(in)[i];
        short4 o;
        o.x = f2bf(v.x); o.y = f2bf(v.y); o.z = f2bf(v.z); o.w = f2bf(v.w);
        reinterpret_cast<short4*>(out)[i] = o;
    }
}

// ---------------- mask dtype probe + canonicalize to u8 ----------------
// bool mask may arrive as int32 (flag 0), uint8 (flag 1) or f32 (flag 2).
__global__ void detect_mask_kernel(const unsigned int* __restrict__ m, int* flag) {
    const int tid = threadIdx.x;
    int gt1 = 0, isf = 0;
    for (int i = 0; i < 4; ++i) {
        unsigned int wv = m[tid + 256 * i];   // 4 KB scan; min buffer is 8 MB
        if (wv > 1u) gt1 = 1;
        if (wv == 0x3F800000u) isf = 1;
    }
    __shared__ int s_gt1, s_isf;
    if (tid == 0) { s_gt1 = 0; s_isf = 0; }
    __syncthreads();
    if (gt1) atomicOr(&s_gt1, 1);
    if (isf) atomicOr(&s_isf, 1);
    __syncthreads();
    if (tid == 0) flag[0] = s_gt1 ? (s_isf ? 2 : 1) : 0;
}

__global__ void canon_mask_kernel(const void* __restrict__ m,
                                  const int* __restrict__ flag,
                                  unsigned char* __restrict__ out, int n) {
    const int f = flag[0];
    int i = blockIdx.x * blockDim.x + threadIdx.x;
    const int stride = gridDim.x * blockDim.x;
    if (f == 0) {
        const int* p = (const int*)m;
        for (; i < n; i += stride) out[i] = p[i] != 0 ? 1 : 0;
    } else if (f == 1) {
        const unsigned char* p = (const unsigned char*)m;
        for (; i < n; i += stride) out[i] = p[i] != 0 ? 1 : 0;
    } else {
        const float* p = (const float*)m;
        for (; i < n; i += stride) out[i] = p[i] != 0.0f ? 1 : 0;
    }
}

// ---------------- GEMM: C = A(MxK) @ B(NxK)^T + bias ----------------
// MODE 0: write bf16 head-split [B,NH,S,HD]   (Q, K projections)
// MODE 1: write bf16 transposed [B,NH,HD,S]   (V projection -> V^T)
// MODE 2: write f32 [M,N]                     (final output proj)
template<int MODE>
__global__ __launch_bounds__(256, 2)
void gemm_bt(const short* __restrict__ A, const short* __restrict__ Bw,
             const float* __restrict__ bias, void* __restrict__ Cout,
             int M, int N, int K) {
    __shared__ short As[128 * 64];
    __shared__ short Bs[128 * 64];
    const int tid  = threadIdx.x;
    const int lane = tid & 63;
    const int w    = tid >> 6;
    const int lo   = lane & 15, hi = lane >> 4;
    const int nbx  = N >> 7;
    const int m0   = (blockIdx.x / nbx) << 7;
    const int n0   = (blockIdx.x % nbx) << 7;
    const int wm   = w >> 1, wn = w & 1;

    f32x4 acc[4][4] = {};

    const int arow = tid >> 3;            // row within 32-row sweep
    const int acol = (tid & 7) * 8;       // element (short) offset in k
    const long aBase = (long)(m0 + arow) * K + acol;
    const long bBase = (long)(n0 + arow) * K + acol;

    for (int k0 = 0; k0 < K; k0 += 64) {
        for (int i = 0; i < 4; ++i) {
            gload_lds16(A  + aBase + (long)i * 32 * K + k0, (char*)As + i * 4096 + tid * 16);
            gload_lds16(Bw + bBase + (long)i * 32 * K + k0, (char*)Bs + i * 4096 + tid * 16);
        }
        __syncthreads();
        for (int ks = 0; ks < 2; ++ks) {
            short8 af[4], bf[4];
            const int koff = ks * 32 + hi * 8;
            for (int fm = 0; fm < 4; ++fm)
                af[fm] = *reinterpret_cast<const short8*>(&As[(wm * 64 + fm * 16 + lo) * 64 + koff]);
            for (int fn = 0; fn < 4; ++fn)
                bf[fn] = *reinterpret_cast<const short8*>(&Bs[(wn * 64 + fn * 16 + lo) * 64 + koff]);
            for (int fm = 0; fm < 4; ++fm)
                for (int fn = 0; fn < 4; ++fn)
                    acc[fm][fn] = __builtin_amdgcn_mfma_f32_16x16x32_bf16(
                        af[fm], bf[fn], acc[fm][fn], 0, 0, 0);
        }
        __syncthreads();
    }

    for (int fm = 0; fm < 4; ++fm) {
        for (int fn = 0; fn < 4; ++fn) {
            const int n = n0 + wn * 64 + fn * 16 + lo;
            const float bv = bias[n];
            for (int r = 0; r < 4; ++r) {
                const int m = m0 + wm * 64 + fm * 16 + hi * 4 + r;
                const float v = acc[fm][fn][r] + bv;
                if (MODE == 2) {
                    ((float*)Cout)[(long)m * N + n] = v;
                } else {
                    const int b = m >> 11, s = m & (SEQ - 1);
                    const int h = n >> 6, d = n & 63;
                    long idx;
                    if (MODE == 0) idx = (((long)(b * NHEADS + h)) * SEQ + s) * HEADD + d;
                    else           idx = (((long)(b * NHEADS + h)) * HEADD + d) * SEQ + s;
                    ((short*)Cout)[idx] = f2bf(v);
                }
            }
        }
    }
}

// ---------------- flash attention ----------------
// grid (S/64, NH, B); 4 waves/block, 16 q-rows per wave; KV tiles of 64.
__global__ __launch_bounds__(256, 2)
void attn_fwd(const short* __restrict__ Qb, const short* __restrict__ Kb,
              const short* __restrict__ Vtb, const float* __restrict__ rel,
              const unsigned char* __restrict__ msk, short* __restrict__ Ob) {
    __shared__ short Ks[64 * 64];
    __shared__ short Vs[64 * 64];
    __shared__ short Ps[4][16 * 64];
    const int tid  = threadIdx.x;
    const int lane = tid & 63;
    const int w    = tid >> 6;
    const int lo   = lane & 15, hi = lane >> 4;
    const int qt = blockIdx.x, h = blockIdx.y, b = blockIdx.z;
    const int bh = b * NHEADS + h;

    // Q fragments: 16 rows x 64 d, row = lo, k contiguous per lane
    short8 qf[2];
    {
        const long qbase = ((long)bh * SEQ + qt * 64 + w * 16 + lo) * HEADD;
        qf[0] = *reinterpret_cast<const short8*>(&Qb[qbase + hi * 8]);
        qf[1] = *reinterpret_cast<const short8*>(&Qb[qbase + 32 + hi * 8]);
    }

    float m_r[4], l_r[4];
    f32x4 oacc[4] = {};
    for (int r = 0; r < 4; ++r) { m_r[r] = -1e30f; l_r[r] = 0.0f; }

    const int srow = tid >> 3;          // 0..31 (staging row within sweep)
    const int scol = (tid & 7) * 16;    // byte column
    const long kgBase = ((long)bh * SEQ + srow) * (HEADD * 2) + scol;     // bytes
    const long vgBase = ((long)bh * HEADD + srow) * ((long)SEQ * 2) + scol;

    for (int kt = 0; kt < SEQ / 64; ++kt) {
        for (int i = 0; i < 2; ++i) {
            gload_lds16((const char*)Kb  + kgBase + (long)kt * 64 * 128 + (long)i * 32 * 128,
                        (char*)Ks + i * 4096 + tid * 16);
            gload_lds16((const char*)Vtb + vgBase + (long)kt * 128 + (long)i * 32 * SEQ * 2,
                        (char*)Vs + i * 4096 + tid * 16);
        }
        __syncthreads();

        // scores: 16 q x 64 kv per wave
        f32x4 sc[4] = {};
        for (int ct = 0; ct < 4; ++ct) {
            short8 kf0 = *reinterpret_cast<const short8*>(&Ks[(ct * 16 + lo) * 64 + hi * 8]);
            short8 kf1 = *reinterpret_cast<const short8*>(&Ks[(ct * 16 + lo) * 64 + 32 + hi * 8]);
            sc[ct] = __builtin_amdgcn_mfma_f32_16x16x32_bf16(qf[0], kf0, sc[ct], 0, 0, 0);
            sc[ct] = __builtin_amdgcn_mfma_f32_16x16x32_bf16(qf[1], kf1, sc[ct], 0, 0, 0);
        }

        // bias + scale + mask  (D layout: row = 4*hi + r, col = 16*ct + lo)
        float sval[4][4];
        const int  qrow_l = w * 16 + hi * 4;
        const long qgBase = ((long)b * SEQ + qt * 64 + qrow_l) * SEQ;
        for (int ct = 0; ct < 4; ++ct) {
            const int kvg = kt * 64 + ct * 16 + lo;
            for (int r = 0; r < 4; ++r) {
                const long ix = qgBase + (long)r * SEQ + kvg;
                const float rv = rel[ix];
                const unsigned char mv = msk[ix];
                sval[ct][r] = mv ? (sc[ct][r] + rv) * 0.125f : -1e30f;
            }
        }

        // online softmax per q-row (16 lanes of same hi-group hold one row)
        for (int r = 0; r < 4; ++r) {
            float tm = fmaxf(fmaxf(sval[0][r], sval[1][r]), fmaxf(sval[2][r], sval[3][r]));
            for (int mk = 1; mk <= 8; mk <<= 1) tm = fmaxf(tm, __shfl_xor(tm, mk, 64));
            const float mn = fmaxf(m_r[r], tm);
            const float sf = __expf(m_r[r] - mn);
            float rs = 0.0f;
            for (int ct = 0; ct < 4; ++ct) {
                const float p = __expf(sval[ct][r] - mn);
                sval[ct][r] = p;
                rs += p;
            }
            for (int mk = 1; mk <= 8; mk <<= 1) rs += __shfl_xor(rs, mk, 64);
            l_r[r] = l_r[r] * sf + rs;
            m_r[r] = mn;
            for (int dt = 0; dt < 4; ++dt) oacc[dt][r] *= sf;
        }

        // P -> LDS (to reach A-fragment layout), then PV
        for (int ct = 0; ct < 4; ++ct)
            for (int r = 0; r < 4; ++r)
                Ps[w][(hi * 4 + r) * 64 + ct * 16 + lo] = f2bf(sval[ct][r]);
        __syncthreads();

        short8 pf0 = *reinterpret_cast<const short8*>(&Ps[w][lo * 64 + hi * 8]);
        short8 pf1 = *reinterpret_cast<const short8*>(&Ps[w][lo * 64 + 32 + hi * 8]);
        for (int dt = 0; dt < 4; ++dt) {
            short8 vf0 = *reinterpret_cast<const short8*>(&Vs[(dt * 16 + lo) * 64 + hi * 8]);
            short8 vf1 = *reinterpret_cast<const short8*>(&Vs[(dt * 16 + lo) * 64 + 32 + hi * 8]);
            oacc[dt] = __builtin_amdgcn_mfma_f32_16x16x32_bf16(pf0, vf0, oacc[dt], 0, 0, 0);
            oacc[dt] = __builtin_amdgcn_mfma_f32_16x16x32_bf16(pf1, vf1, oacc[dt], 0, 0, 0);
        }
        __syncthreads();
    }

    // epilogue: write attn output bf16 into [B,S,H] (head-merged)
    for (int r = 0; r < 4; ++r) {
        const int qg = qt * 64 + w * 16 + hi * 4 + r;
        const float inv = (l_r[r] > 0.0f && m_r[r] > -1e29f) ? 1.0f / l_r[r] : 0.0f;
        for (int dt = 0; dt < 4; ++dt) {
            const int d = dt * 16 + lo;
            Ob[((long)b * SEQ + qg) * HDIM + h * 64 + d] = f2bf(oacc[dt][r] * inv);
        }
    }
}

// ---------------- host launch ----------------
extern "C" void kernel_launch(void* const* d_in, const int* in_sizes, int n_in,
                              void* d_out, int out_size, void* d_ws, size_t ws_size,
                              hipStream_t stream) {
    const float* q    = (const float*)d_in[0];
    const float* k    = (const float*)d_in[1];
    const float* v    = (const float*)d_in[2];
    const void*  mask = d_in[3];
    const float* rel  = (const float*)d_in[4];
    const float* Wq   = (const float*)d_in[5];
    const float* bq   = (const float*)d_in[6];
    const float* Wk   = (const float*)d_in[7];
    const float* bk   = (const float*)d_in[8];
    const float* Wv   = (const float*)d_in[9];
    const float* bv   = (const float*)d_in[10];
    const float* Wo   = (const float*)d_in[11];
    const float* bo   = (const float*)d_in[12];
    (void)in_sizes; (void)n_in; (void)out_size; (void)ws_size;

    char* ws = (char*)d_ws;
    size_t off = 0;
    auto alloc = [&](size_t bytes) {
        char* p = ws + off;
        off += (bytes + 255) & ~(size_t)255;
        return p;
    };
    const size_t xBytes = (size_t)MROWS * HDIM * 2;   // 8 MB bf16
    const size_t wBytes = (size_t)HDIM * HDIM * 2;    // 2 MB bf16

    short* xq = (short*)alloc(xBytes);
    short* xk = (short*)alloc(xBytes);
    short* xv = (short*)alloc(xBytes);
    short* wqb = (short*)alloc(wBytes);
    short* wkb = (short*)alloc(wBytes);
    short* wvb = (short*)alloc(wBytes);
    short* wob = (short*)alloc(wBytes);
    short* Qb  = (short*)alloc(xBytes);
    short* Kb  = (short*)alloc(xBytes);
    short* Vt  = (short*)alloc(xBytes);
    short* Ab  = (short*)alloc(xBytes);               // attention out, bf16 [B,S,H]
    unsigned char* m8 = (unsigned char*)alloc((size_t)MASK_N);
    int* flag = (int*)alloc(256);

    const int CV_BLOCKS = 1024, CV_T = 256;
    const int n4x = MROWS * HDIM / 4, n4w = HDIM * HDIM / 4;
    f32_to_bf16_kernel<<<CV_BLOCKS, CV_T, 0, stream>>>(q,  xq,  n4x);
    f32_to_bf16_kernel<<<CV_BLOCKS, CV_T, 0, stream>>>(k,  xk,  n4x);
    f32_to_bf16_kernel<<<CV_BLOCKS, CV_T, 0, stream>>>(v,  xv,  n4x);
    f32_to_bf16_kernel<<<CV_BLOCKS, CV_T, 0, stream>>>(Wq, wqb, n4w);
    f32_to_bf16_kernel<<<CV_BLOCKS, CV_T, 0, stream>>>(Wk, wkb, n4w);
    f32_to_bf16_kernel<<<CV_BLOCKS, CV_T, 0, stream>>>(Wv, wvb, n4w);
    f32_to_bf16_kernel<<<CV_BLOCKS, CV_T, 0, stream>>>(Wo, wob, n4w);

    detect_mask_kernel<<<1, 256, 0, stream>>>((const unsigned int*)mask, flag);
    canon_mask_kernel<<<2048, 256, 0, stream>>>(mask, flag, m8, (int)MASK_N);

    const int gemmGrid = (MROWS / 128) * (HDIM / 128);   // 256 blocks
    gemm_bt<0><<<gemmGrid, 256, 0, stream>>>(xq, wqb, bq, Qb, MROWS, HDIM, HDIM);
    gemm_bt<0><<<gemmGrid, 256, 0, stream>>>(xk, wkb, bk, Kb, MROWS, HDIM, HDIM);
    gemm_bt<1><<<gemmGrid, 256, 0, stream>>>(xv, wvb, bv, Vt, MROWS, HDIM, HDIM);

    attn_fwd<<<dim3(SEQ / 64, NHEADS, BATCH), 256, 0, stream>>>(Qb, Kb, Vt, rel, m8, Ab);

    gemm_bt<2><<<gemmGrid, 256, 0, stream>>>(Ab, wob, bo, d_out, MROWS, HDIM, HDIM);
}

// Round 2
// 242.686 us; speedup vs baseline: 1.4900x; 1.4900x over previous
//
#include <hip/hip_runtime.h>
#include <hip/hip_bf16.h>

// Problem constants
constexpr int BATCH = 2, SEQ = 2048, HDIM = 1024, NHEADS = 16, HEADD = 64;
constexpr int MROWS = BATCH * SEQ;            // 4096

typedef short short8 __attribute__((ext_vector_type(8)));
typedef float f32x4  __attribute__((ext_vector_type(4)));

static __device__ __forceinline__ short f2bf(float f) {
    __hip_bfloat16 h = __float2bfloat16(f);
    return *reinterpret_cast<short*>(&h);
}

static __device__ __forceinline__ void gload_lds16(const void* g, void* l) {
    __builtin_amdgcn_global_load_lds(
        (const __attribute__((address_space(1))) unsigned int*)g,
        (__attribute__((address_space(3))) unsigned int*)l, 16, 0, 0);
}

// ---------------- conversions: f32 -> bf16 (x4 vectorized, fused) ----------------
__global__ void cvt_qkv_kernel(const float* __restrict__ q, const float* __restrict__ k,
                               const float* __restrict__ v, short* __restrict__ xq,
                               short* __restrict__ xk, short* __restrict__ xv, int n4) {
    int i = blockIdx.x * blockDim.x + threadIdx.x;
    const int stride = gridDim.x * blockDim.x;
    for (; i < 3 * n4; i += stride) {
        const float* in; short* out; int j = i;
        if (j >= 2 * n4)      { in = v; out = xv; j -= 2 * n4; }
        else if (j >= n4)     { in = k; out = xk; j -= n4; }
        else                  { in = q; out = xq; }
        const float4 val = reinterpret_cast<const float4*>(in)[j];
        short4 o;
        o.x = f2bf(val.x); o.y = f2bf(val.y); o.z = f2bf(val.z); o.w = f2bf(val.w);
        reinterpret_cast<short4*>(out)[j] = o;
    }
}

__global__ void cvt_w4_kernel(const float* __restrict__ w0, const float* __restrict__ w1,
                              const float* __restrict__ w2, const float* __restrict__ w3,
                              short* __restrict__ o0, short* __restrict__ o1,
                              short* __restrict__ o2, short* __restrict__ o3, int n4) {
    int i = blockIdx.x * blockDim.x + threadIdx.x;
    const int stride = gridDim.x * blockDim.x;
    for (; i < 4 * n4; i += stride) {
        const float* in; short* out; int j = i;
        if (j >= 3 * n4)      { in = w3; out = o3; j -= 3 * n4; }
        else if (j >= 2 * n4) { in = w2; out = o2; j -= 2 * n4; }
        else if (j >= n4)     { in = w1; out = o1; j -= n4; }
        else                  { in = w0; out = o0; }
        const float4 val = reinterpret_cast<const float4*>(in)[j];
        short4 o;
        o.x = f2bf(val.x); o.y = f2bf(val.y); o.z = f2bf(val.z); o.w = f2bf(val.w);
        reinterpret_cast<short4*>(out)[j] = o;
    }
}

// ---------------- mask dtype probe ----------------
// bool mask may arrive as int32 (flag 0), uint8 (flag 1) or f32 (flag 2).
__global__ void detect_mask_kernel(const unsigned int* __restrict__ m, int* flag) {
    const int tid = threadIdx.x;
    int gt1 = 0, isf = 0;
    for (int i = 0; i < 4; ++i) {
        unsigned int wv = m[tid + 256 * i];   // 4 KB scan; min buffer is 8 MB
        if (wv > 1u) gt1 = 1;
        if (wv == 0x3F800000u) isf = 1;
    }
    __shared__ int s_gt1, s_isf;
    if (tid == 0) { s_gt1 = 0; s_isf = 0; }
    __syncthreads();
    if (gt1) atomicOr(&s_gt1, 1);
    if (isf) atomicOr(&s_isf, 1);
    __syncthreads();
    if (tid == 0) flag[0] = s_gt1 ? (s_isf ? 2 : 1) : 0;
}

// ---------------- fuse mask + rel -> relm, repacked layout ----------------
// relm float4-index [(b*512 + q/4)*2048 + k], components j = q%3.. q&3:
//   relm[...][j] = mask[b][q][k] ? rel[b][q][k] * 0.125f : -1e30f
__global__ void fuse_rel_kernel(const float* __restrict__ rel, const void* __restrict__ mask,
                                const int* __restrict__ flag, float* __restrict__ relm,
                                int nPos) {   // nPos = BATCH*512*2048
    const int f = flag[0];
    int i = blockIdx.x * blockDim.x + threadIdx.x;
    const int stride = gridDim.x * blockDim.x;
    for (; i < nPos; i += stride) {
        const int b  = i >> 20;            // 512*2048 = 2^20
        const int qq = (i >> 11) & 511;
        const int k  = i & 2047;
        const long src = (((long)b * SEQ + qq * 4)) * SEQ + k;
        float4 o;
        float* op = reinterpret_cast<float*>(&o);
        for (int j = 0; j < 4; ++j) {
            const long s = src + (long)j * SEQ;
            const float v = rel[s];
            bool m;
            if (f == 0)      m = ((const int*)mask)[s] != 0;
            else if (f == 1) m = ((const unsigned char*)mask)[s] != 0;
            else             m = ((const float*)mask)[s] != 0.0f;
            op[j] = m ? v * 0.125f : -1e30f;
        }
        reinterpret_cast<float4*>(relm)[i] = o;
    }
}

// ---------------- GEMM: C = (A(MxK) @ B(NxK)^T + bias) * scale ----------------
// MODE 0: write bf16 head-split [B,NH,S,HD]   (Q, K projections)
// MODE 1: write bf16 transposed [B,NH,HD,S]   (V projection -> V^T)
// MODE 2: write f32 [M,N]                     (final output proj)
template<int MODE>
__global__ __launch_bounds__(256, 2)
void gemm_bt(const short* __restrict__ A, const short* __restrict__ Bw,
             const float* __restrict__ bias, void* __restrict__ Cout,
             int M, int N, int K, float scale) {
    __shared__ short As[128 * 64];
    __shared__ short Bs[128 * 64];
    const int tid  = threadIdx.x;
    const int lane = tid & 63;
    const int w    = tid >> 6;
    const int lo   = lane & 15, hi = lane >> 4;
    const int nbx  = N >> 7;
    const int m0   = (blockIdx.x / nbx) << 7;
    const int n0   = (blockIdx.x % nbx) << 7;
    const int wm   = w >> 1, wn = w & 1;

    f32x4 acc[4][4] = {};

    const int arow = tid >> 3;            // row within 32-row sweep
    const int acol = (tid & 7) * 8;       // element (short) offset in k
    const long aBase = (long)(m0 + arow) * K + acol;
    const long bBase = (long)(n0 + arow) * K + acol;

    for (int k0 = 0; k0 < K; k0 += 64) {
        for (int i = 0; i < 4; ++i) {
            gload_lds16(A  + aBase + (long)i * 32 * K + k0, (char*)As + i * 4096 + tid * 16);
            gload_lds16(Bw + bBase + (long)i * 32 * K + k0, (char*)Bs + i * 4096 + tid * 16);
        }
        __syncthreads();
        for (int ks = 0; ks < 2; ++ks) {
            short8 af[4], bf[4];
            const int koff = ks * 32 + hi * 8;
            for (int fm = 0; fm < 4; ++fm)
                af[fm] = *reinterpret_cast<const short8*>(&As[(wm * 64 + fm * 16 + lo) * 64 + koff]);
            for (int fn = 0; fn < 4; ++fn)
                bf[fn] = *reinterpret_cast<const short8*>(&Bs[(wn * 64 + fn * 16 + lo) * 64 + koff]);
            for (int fm = 0; fm < 4; ++fm)
                for (int fn = 0; fn < 4; ++fn)
                    acc[fm][fn] = __builtin_amdgcn_mfma_f32_16x16x32_bf16(
                        af[fm], bf[fn], acc[fm][fn], 0, 0, 0);
        }
        __syncthreads();
    }

    for (int fm = 0; fm < 4; ++fm) {
        for (int fn = 0; fn < 4; ++fn) {
            const int n = n0 + wn * 64 + fn * 16 + lo;
            const float bv = bias[n];
            for (int r = 0; r < 4; ++r) {
                const int m = m0 + wm * 64 + fm * 16 + hi * 4 + r;
                const float v = (acc[fm][fn][r] + bv) * scale;
                if (MODE == 2) {
                    ((float*)Cout)[(long)m * N + n] = v;
                } else {
                    const int b = m >> 11, s = m & (SEQ - 1);
                    const int h = n >> 6, d = n & 63;
                    long idx;
                    if (MODE == 0) idx = (((long)(b * NHEADS + h)) * SEQ + s) * HEADD + d;
                    else           idx = (((long)(b * NHEADS + h)) * HEADD + d) * SEQ + s;
                    ((short*)Cout)[idx] = f2bf(v);
                }
            }
        }
    }
}

// ---------------- flash attention ----------------
// grid (S/64, NH, B); 4 waves/block, 16 q-rows per wave; KV tiles of 64.
// Double-buffered K/V staging (2-phase), XOR-swizzled LDS, relm as MFMA C-init.
__global__ __launch_bounds__(256, 4)
void attn_fwd(const short* __restrict__ Qb, const short* __restrict__ Kb,
              const short* __restrict__ Vtb, const float* __restrict__ relm,
              short* __restrict__ Ob) {
    __shared__ short Ks[2][64 * 64];
    __shared__ short Vs[2][64 * 64];
    __shared__ short Ps[4][16 * 64];
    const int tid  = threadIdx.x;
    const int lane = tid & 63;
    const int w    = tid >> 6;
    const int lo   = lane & 15, hi = lane >> 4;
    const int qt = blockIdx.x, h = blockIdx.y, b = blockIdx.z;
    const int bh = b * NHEADS + h;

    // Q fragments: 16 rows x 64 d (Q is pre-scaled by 0.125 in its projection)
    short8 qf[2];
    {
        const long qbase = ((long)bh * SEQ + qt * 64 + w * 16 + lo) * HEADD;
        qf[0] = *reinterpret_cast<const short8*>(&Qb[qbase + hi * 8]);
        qf[1] = *reinterpret_cast<const short8*>(&Qb[qbase + 32 + hi * 8]);
    }

    float m_r[4], l_r[4];
    f32x4 oacc[4] = {};
    for (int r = 0; r < 4; ++r) { m_r[r] = -1e30f; l_r[r] = 0.0f; }

    // staging geometry (pre-swizzled global source -> linear LDS dest)
    const int srow  = tid >> 3;                 // 0..31
    const int scolb = (tid & 7) * 16;           // byte column 0..112
    const int scolK = scolb ^ ((srow & 7) << 4);
    const char* KbB = (const char*)Kb + ((long)bh * SEQ + srow) * 128 + scolK;
    const char* VbB = (const char*)Vtb + ((long)bh * HEADD + srow) * ((long)SEQ * 2) + scolK;

    auto stage = [&](int buf, int kt) {
        for (int i = 0; i < 2; ++i) {
            gload_lds16(KbB + ((long)kt * 64 + i * 32) * 128,
                        (char*)&Ks[buf][0] + i * 4096 + tid * 16);
            gload_lds16(VbB + (long)i * 32 * (SEQ * 2) + (long)kt * 128,
                        (char*)&Vs[buf][0] + i * 4096 + tid * 16);
        }
    };

    stage(0, 0);
    __syncthreads();

    const int rsw = (lo & 7) << 4;              // read-side swizzle (row&7)<<4, row%8==lo%8
    const f32x4* r4 = (const f32x4*)relm;
    const long rbase = ((long)b * 512 + qt * 16 + w * 4 + hi) * 2048 + lo;

    for (int kt = 0; kt < SEQ / 64; ++kt) {
        const int cb = kt & 1;
        if (kt < SEQ / 64 - 1) stage(cb ^ 1, kt + 1);

        // scores init = premasked, prescaled bias (C-init); then QK^T on top
        f32x4 sc[4];
        for (int ct = 0; ct < 4; ++ct)
            sc[ct] = r4[rbase + kt * 64 + ct * 16];

        const char* kls = (const char*)&Ks[cb][0];
        for (int ct = 0; ct < 4; ++ct) {
            const int row = ct * 16 + lo;
            short8 kf0 = *(const short8*)(kls + row * 128 + ((hi * 16) ^ rsw));
            short8 kf1 = *(const short8*)(kls + row * 128 + ((64 + hi * 16) ^ rsw));
            sc[ct] = __builtin_amdgcn_mfma_f32_16x16x32_bf16(qf[0], kf0, sc[ct], 0, 0, 0);
            sc[ct] = __builtin_amdgcn_mfma_f32_16x16x32_bf16(qf[1], kf1, sc[ct], 0, 0, 0);
        }

        // online softmax per q-row (16 lanes of same hi-group hold one row)
        for (int r = 0; r < 4; ++r) {
            float tm = fmaxf(fmaxf(sc[0][r], sc[1][r]), fmaxf(sc[2][r], sc[3][r]));
            for (int mk = 1; mk <= 8; mk <<= 1) tm = fmaxf(tm, __shfl_xor(tm, mk, 64));
            const float mn = fmaxf(m_r[r], tm);
            const float sf = __expf(m_r[r] - mn);
            float rs = 0.0f;
            for (int ct = 0; ct < 4; ++ct) {
                const float p = __expf(sc[ct][r] - mn);
                sc[ct][r] = p;
                rs += p;
            }
            for (int mk = 1; mk <= 8; mk <<= 1) rs += __shfl_xor(rs, mk, 64);
            l_r[r] = l_r[r] * sf + rs;
            m_r[r] = mn;
            for (int dt = 0; dt < 4; ++dt) oacc[dt][r] *= sf;
        }

        // P -> per-wave LDS (swizzled, no barrier needed), then PV
        char* pls = (char*)&Ps[w][0];
        for (int ct = 0; ct < 4; ++ct)
            for (int r = 0; r < 4; ++r) {
                const int row = hi * 4 + r;
                *(short*)(pls + row * 128 + ((ct * 32 + lo * 2) ^ ((row & 7) << 4))) =
                    f2bf(sc[ct][r]);
            }

        short8 pf0 = *(const short8*)(pls + lo * 128 + ((hi * 16) ^ rsw));
        short8 pf1 = *(const short8*)(pls + lo * 128 + ((64 + hi * 16) ^ rsw));
        const char* vls = (const char*)&Vs[cb][0];
        for (int dt = 0; dt < 4; ++dt) {
            const int row = dt * 16 + lo;
            short8 vf0 = *(const short8*)(vls + row * 128 + ((hi * 16) ^ rsw));
            short8 vf1 = *(const short8*)(vls + row * 128 + ((64 + hi * 16) ^ rsw));
            oacc[dt] = __builtin_amdgcn_mfma_f32_16x16x32_bf16(pf0, vf0, oacc[dt], 0, 0, 0);
            oacc[dt] = __builtin_amdgcn_mfma_f32_16x16x32_bf16(pf1, vf1, oacc[dt], 0, 0, 0);
        }
        __syncthreads();
    }

    // epilogue: write attn output bf16 into [B,S,H] (head-merged)
    for (int r = 0; r < 4; ++r) {
        const int qg = qt * 64 + w * 16 + hi * 4 + r;
        const float inv = (l_r[r] > 0.0f && m_r[r] > -1e29f) ? 1.0f / l_r[r] : 0.0f;
        for (int dt = 0; dt < 4; ++dt) {
            const int d = dt * 16 + lo;
            Ob[((long)b * SEQ + qg) * HDIM + h * 64 + d] = f2bf(oacc[dt][r] * inv);
        }
    }
}

// ---------------- host launch ----------------
extern "C" void kernel_launch(void* const* d_in, const int* in_sizes, int n_in,
                              void* d_out, int out_size, void* d_ws, size_t ws_size,
                              hipStream_t stream) {
    const float* q    = (const float*)d_in[0];
    const float* k    = (const float*)d_in[1];
    const float* v    = (const float*)d_in[2];
    const void*  mask = d_in[3];
    const float* rel  = (const float*)d_in[4];
    const float* Wq   = (const float*)d_in[5];
    const float* bq   = (const float*)d_in[6];
    const float* Wk   = (const float*)d_in[7];
    const float* bk   = (const float*)d_in[8];
    const float* Wv   = (const float*)d_in[9];
    const float* bv   = (const float*)d_in[10];
    const float* Wo   = (const float*)d_in[11];
    const float* bo   = (const float*)d_in[12];
    (void)in_sizes; (void)n_in; (void)out_size; (void)ws_size;

    char* ws = (char*)d_ws;
    size_t off = 0;
    auto alloc = [&](size_t bytes) {
        char* p = ws + off;
        off += (bytes + 255) & ~(size_t)255;
        return p;
    };
    const size_t xBytes = (size_t)MROWS * HDIM * 2;      // 8 MB bf16
    const size_t wBytes = (size_t)HDIM * HDIM * 2;       // 2 MB bf16
    const int    relPos = BATCH * 512 * 2048;            // float4 count
    const size_t relBytes = (size_t)relPos * 16;         // 32 MB f32

    // persistent region
    short* Qb  = (short*)alloc(xBytes);
    short* Kb  = (short*)alloc(xBytes);
    short* Vt  = (short*)alloc(xBytes);
    short* wob = (short*)alloc(wBytes);
    int*   flag = (int*)alloc(256);
    // pool: phase 1 = xq,xk,xv,wqb,wkb,wvb (30 MB); phase 2 = relm (32 MB)
    char* pool = (char*)alloc(relBytes);
    short* Ab  = (short*)alloc(xBytes);

    short* xq  = (short*)(pool);
    short* xk  = (short*)(pool + xBytes);
    short* xv  = (short*)(pool + 2 * xBytes);
    short* wqb = (short*)(pool + 3 * xBytes);
    short* wkb = (short*)(pool + 3 * xBytes + wBytes);
    short* wvb = (short*)(pool + 3 * xBytes + 2 * wBytes);
    float* relm = (float*)pool;

    const int n4x = MROWS * HDIM / 4, n4w = HDIM * HDIM / 4;
    cvt_qkv_kernel<<<1024, 256, 0, stream>>>(q, k, v, xq, xk, xv, n4x);
    cvt_w4_kernel<<<512, 256, 0, stream>>>(Wq, Wk, Wv, Wo, wqb, wkb, wvb, wob, n4w);
    detect_mask_kernel<<<1, 256, 0, stream>>>((const unsigned int*)mask, flag);

    const int gemmGrid = (MROWS / 128) * (HDIM / 128);   // 256 blocks
    gemm_bt<0><<<gemmGrid, 256, 0, stream>>>(xq, wqb, bq, Qb, MROWS, HDIM, HDIM, 0.125f);
    gemm_bt<0><<<gemmGrid, 256, 0, stream>>>(xk, wkb, bk, Kb, MROWS, HDIM, HDIM, 1.0f);
    gemm_bt<1><<<gemmGrid, 256, 0, stream>>>(xv, wvb, bv, Vt, MROWS, HDIM, HDIM, 1.0f);

    // pool is dead for x/w now; build relm over it
    fuse_rel_kernel<<<2048, 256, 0, stream>>>(rel, mask, flag, relm, relPos);

    attn_fwd<<<dim3(SEQ / 64, NHEADS, BATCH), 256, 0, stream>>>(Qb, Kb, Vt, relm, Ab);

    gemm_bt<2><<<gemmGrid, 256, 0, stream>>>(Ab, wob, bo, d_out, MROWS, HDIM, HDIM, 1.0f);
}

// Round 3
// 185.658 us; speedup vs baseline: 1.9476x; 1.3072x over previous
//
#include <hip/hip_runtime.h>
#include <hip/hip_bf16.h>

// Problem constants
constexpr int BATCH = 2, SEQ = 2048, HDIM = 1024, NHEADS = 16, HEADD = 64;
constexpr int MROWS = BATCH * SEQ;            // 4096
// fold attention scale and exp->exp2 conversion: c = 0.125 / ln(2)
constexpr float QSCALE = 0.18033688011112042f;

typedef short short8 __attribute__((ext_vector_type(8)));
typedef float f32x4  __attribute__((ext_vector_type(4)));

static __device__ __forceinline__ short f2bf(float f) {
    __hip_bfloat16 h = __float2bfloat16(f);
    return *reinterpret_cast<short*>(&h);
}

static __device__ __forceinline__ void gload_lds16(const void* g, void* l) {
    __builtin_amdgcn_global_load_lds(
        (const __attribute__((address_space(1))) unsigned int*)g,
        (__attribute__((address_space(3))) unsigned int*)l, 16, 0, 0);
}

// ---------------- conversions: f32 -> bf16 (x4 vectorized, fused) ----------------
__global__ void cvt_qkv_kernel(const float* __restrict__ q, const float* __restrict__ k,
                               const float* __restrict__ v, short* __restrict__ xq,
                               short* __restrict__ xk, short* __restrict__ xv, int n4) {
    int i = blockIdx.x * blockDim.x + threadIdx.x;
    const int stride = gridDim.x * blockDim.x;
    for (; i < 3 * n4; i += stride) {
        const float* in; short* out; int j = i;
        if (j >= 2 * n4)      { in = v; out = xv; j -= 2 * n4; }
        else if (j >= n4)     { in = k; out = xk; j -= n4; }
        else                  { in = q; out = xq; }
        const float4 val = reinterpret_cast<const float4*>(in)[j];
        short4 o;
        o.x = f2bf(val.x); o.y = f2bf(val.y); o.z = f2bf(val.z); o.w = f2bf(val.w);
        reinterpret_cast<short4*>(out)[j] = o;
    }
}

__global__ void cvt_w4_kernel(const float* __restrict__ w0, const float* __restrict__ w1,
                              const float* __restrict__ w2, const float* __restrict__ w3,
                              short* __restrict__ o0, short* __restrict__ o1,
                              short* __restrict__ o2, short* __restrict__ o3, int n4) {
    int i = blockIdx.x * blockDim.x + threadIdx.x;
    const int stride = gridDim.x * blockDim.x;
    for (; i < 4 * n4; i += stride) {
        const float* in; short* out; int j = i;
        if (j >= 3 * n4)      { in = w3; out = o3; j -= 3 * n4; }
        else if (j >= 2 * n4) { in = w2; out = o2; j -= 2 * n4; }
        else if (j >= n4)     { in = w1; out = o1; j -= n4; }
        else                  { in = w0; out = o0; }
        const float4 val = reinterpret_cast<const float4*>(in)[j];
        short4 o;
        o.x = f2bf(val.x); o.y = f2bf(val.y); o.z = f2bf(val.z); o.w = f2bf(val.w);
        reinterpret_cast<short4*>(out)[j] = o;
    }
}

// ---------------- mask dtype probe ----------------
__global__ void detect_mask_kernel(const unsigned int* __restrict__ m, int* flag) {
    const int tid = threadIdx.x;
    int gt1 = 0, isf = 0;
    for (int i = 0; i < 4; ++i) {
        unsigned int wv = m[tid + 256 * i];
        if (wv > 1u) gt1 = 1;
        if (wv == 0x3F800000u) isf = 1;
    }
    __shared__ int s_gt1, s_isf;
    if (tid == 0) { s_gt1 = 0; s_isf = 0; }
    __syncthreads();
    if (gt1) atomicOr(&s_gt1, 1);
    if (isf) atomicOr(&s_isf, 1);
    __syncthreads();
    if (tid == 0) flag[0] = s_gt1 ? (s_isf ? 2 : 1) : 0;
}

// ---------------- fuse mask + rel -> relm, repacked layout ----------------
// relm float4-index [(b*512 + q/4)*2048 + k], component j = q%4:
//   relm[...][j] = mask[b][q][k] ? rel[b][q][k] * QSCALE : -1e30f
__global__ void fuse_rel_kernel(const float* __restrict__ rel, const void* __restrict__ mask,
                                const int* __restrict__ flag, float* __restrict__ relm,
                                int nPos) {   // nPos = BATCH*512*2048
    const int f = flag[0];
    int i = blockIdx.x * blockDim.x + threadIdx.x;
    const int stride = gridDim.x * blockDim.x;
    for (; i < nPos; i += stride) {
        const int b  = i >> 20;            // 512*2048 = 2^20
        const int qq = (i >> 11) & 511;
        const int k  = i & 2047;
        const long src = (((long)b * SEQ + qq * 4)) * SEQ + k;
        float4 o;
        float* op = reinterpret_cast<float*>(&o);
        for (int j = 0; j < 4; ++j) {
            const long s = src + (long)j * SEQ;
            const float v = rel[s];
            bool m;
            if (f == 0)      m = ((const int*)mask)[s] != 0;
            else if (f == 1) m = ((const unsigned char*)mask)[s] != 0;
            else             m = ((const float*)mask)[s] != 0.0f;
            op[j] = m ? v * QSCALE : -1e30f;
        }
        reinterpret_cast<float4*>(relm)[i] = o;
    }
}

// ================= GEMM core (128x128 tile, BK=64, 2-phase) =================
// Computes acc for C = A(MxK) @ B(NxK)^T.  Epilogue handled by caller wrapper.
template<typename EPI>
static __device__ __forceinline__
void gemm_core(const short* A, const short* Bw, int K, int m0, int n0, EPI epi) {
    __shared__ short As[128 * 64];
    __shared__ short Bs[128 * 64];
    const int tid  = threadIdx.x;
    const int lane = tid & 63;
    const int w    = tid >> 6;
    const int lo   = lane & 15, hi = lane >> 4;
    const int wm   = w >> 1, wn = w & 1;

    f32x4 acc[4][4] = {};

    const int arow = tid >> 3;
    const int acol = (tid & 7) * 8;
    const long aBase = (long)(m0 + arow) * K + acol;
    const long bBase = (long)(n0 + arow) * K + acol;

    for (int k0 = 0; k0 < K; k0 += 64) {
        for (int i = 0; i < 4; ++i) {
            gload_lds16(A  + aBase + (long)i * 32 * K + k0, (char*)As + i * 4096 + tid * 16);
            gload_lds16(Bw + bBase + (long)i * 32 * K + k0, (char*)Bs + i * 4096 + tid * 16);
        }
        __syncthreads();
        for (int ks = 0; ks < 2; ++ks) {
            short8 af[4], bf[4];
            const int koff = ks * 32 + hi * 8;
            for (int fm = 0; fm < 4; ++fm)
                af[fm] = *reinterpret_cast<const short8*>(&As[(wm * 64 + fm * 16 + lo) * 64 + koff]);
            for (int fn = 0; fn < 4; ++fn)
                bf[fn] = *reinterpret_cast<const short8*>(&Bs[(wn * 64 + fn * 16 + lo) * 64 + koff]);
            for (int fm = 0; fm < 4; ++fm)
                for (int fn = 0; fn < 4; ++fn)
                    acc[fm][fn] = __builtin_amdgcn_mfma_f32_16x16x32_bf16(
                        af[fm], bf[fn], acc[fm][fn], 0, 0, 0);
        }
        __syncthreads();
    }

    for (int fm = 0; fm < 4; ++fm)
        for (int fn = 0; fn < 4; ++fn) {
            const int n = n0 + wn * 64 + fn * 16 + lo;
            const int mB = m0 + wm * 64 + fm * 16 + hi * 4;
            for (int r = 0; r < 4; ++r) epi(mB + r, n, acc[fm][fn][r]);
        }
}

// merged Q/K/V projection: grid = 3*256 blocks; which = blockIdx.x>>8
__global__ __launch_bounds__(256, 2)
void qkv_gemm(const short* xq, const short* xk, const short* xv,
              const short* wq, const short* wk, const short* wv,
              const float* bq, const float* bk, const float* bv,
              short* Qb, short* Kb, short* Vt) {
    const int which = blockIdx.x >> 8;
    const int bid   = blockIdx.x & 255;
    const int m0 = (bid >> 3) << 7;       // 32 m-tiles
    const int n0 = (bid & 7) << 7;        // 8 n-tiles
    const short* A    = which == 0 ? xq : which == 1 ? xk : xv;
    const short* W    = which == 0 ? wq : which == 1 ? wk : wv;
    const float* bias = which == 0 ? bq : which == 1 ? bk : bv;
    short* C          = which == 0 ? Qb : which == 1 ? Kb : Vt;
    const float scale = which == 0 ? QSCALE : 1.0f;
    gemm_core(A, W, HDIM, m0, n0, [&](int m, int n, float v) {
        v = (v + bias[n]) * scale;
        const int b = m >> 11, s = m & (SEQ - 1);
        const int h = n >> 6, d = n & 63;
        long idx;
        if (which != 2) idx = (((long)(b * NHEADS + h)) * SEQ + s) * HEADD + d;
        else            idx = (((long)(b * NHEADS + h)) * HEADD + d) * SEQ + s;
        C[idx] = f2bf(v);
    });
}

// final output projection: f32 out [M,N]
__global__ __launch_bounds__(256, 2)
void out_gemm(const short* A, const short* W, const float* bias,
              float* Cout) {
    const int bid = blockIdx.x;
    const int m0 = (bid >> 3) << 7;
    const int n0 = (bid & 7) << 7;
    gemm_core(A, W, HDIM, m0, n0, [&](int m, int n, float v) {
        Cout[(long)m * HDIM + n] = v + bias[n];
    });
}

// ---------------- flash attention ----------------
// grid 1024 (XCD-chunk swizzled); 4 waves/block, 16 q-rows per wave; KV tiles of 64.
// Fixed-shift softmax (no max tracking), deferred row-sum reduce, exp2 domain.
__global__ __launch_bounds__(256, 4)
void attn_fwd(const short* __restrict__ Qb, const short* __restrict__ Kb,
              const short* __restrict__ Vtb, const float* __restrict__ relm,
              short* __restrict__ Ob) {
    __shared__ short Ks[2][64 * 64];
    __shared__ short Vs[2][64 * 64];
    __shared__ short Ps[4][16 * 64];
    const int tid  = threadIdx.x;
    const int lane = tid & 63;
    const int w    = tid >> 6;
    const int lo   = lane & 15, hi = lane >> 4;
    // XCD-chunked swizzle: 1024 blocks, 8 XCDs -> each XCD owns 128 contiguous wgs
    const int wg = ((blockIdx.x & 7) << 7) + (blockIdx.x >> 3);
    const int qt = wg & 31, h = (wg >> 5) & 15, b = wg >> 9;
    const int bh = b * NHEADS + h;

    // Q fragments: 16 rows x 64 d (Q pre-scaled by QSCALE in its projection)
    short8 qf[2];
    {
        const long qbase = ((long)bh * SEQ + qt * 64 + w * 16 + lo) * HEADD;
        qf[0] = *reinterpret_cast<const short8*>(&Qb[qbase + hi * 8]);
        qf[1] = *reinterpret_cast<const short8*>(&Qb[qbase + 32 + hi * 8]);
    }

    float lsum[4] = {};
    f32x4 oacc[4] = {};

    // staging geometry (pre-swizzled global source -> linear LDS dest)
    const int srow  = tid >> 3;
    const int scolb = (tid & 7) * 16;
    const int scolK = scolb ^ ((srow & 7) << 4);
    const char* KbB = (const char*)Kb + ((long)bh * SEQ + srow) * 128 + scolK;
    const char* VbB = (const char*)Vtb + ((long)bh * HEADD + srow) * ((long)SEQ * 2) + scolK;

    auto stage = [&](int buf, int kt) {
        for (int i = 0; i < 2; ++i) {
            gload_lds16(KbB + ((long)kt * 64 + i * 32) * 128,
                        (char*)&Ks[buf][0] + i * 4096 + tid * 16);
            gload_lds16(VbB + (long)i * 32 * (SEQ * 2) + (long)kt * 128,
                        (char*)&Vs[buf][0] + i * 4096 + tid * 16);
        }
    };

    stage(0, 0);
    __syncthreads();

    const int rsw = (lo & 7) << 4;
    const f32x4* r4 = (const f32x4*)relm;
    const long rbase = ((long)b * 512 + qt * 16 + w * 4 + hi) * 2048 + lo;

    for (int kt = 0; kt < SEQ / 64; ++kt) {
        const int cb = kt & 1;
        if (kt < SEQ / 64 - 1) stage(cb ^ 1, kt + 1);

        // scores init = premasked, prescaled bias (C-init); then QK^T on top
        f32x4 sc[4];
        for (int ct = 0; ct < 4; ++ct)
            sc[ct] = r4[rbase + kt * 64 + ct * 16];

        const char* kls = (const char*)&Ks[cb][0];
        for (int ct = 0; ct < 4; ++ct) {
            const int row = ct * 16 + lo;
            short8 kf0 = *(const short8*)(kls + row * 128 + ((hi * 16) ^ rsw));
            short8 kf1 = *(const short8*)(kls + row * 128 + ((64 + hi * 16) ^ rsw));
            sc[ct] = __builtin_amdgcn_mfma_f32_16x16x32_bf16(qf[0], kf0, sc[ct], 0, 0, 0);
            sc[ct] = __builtin_amdgcn_mfma_f32_16x16x32_bf16(qf[1], kf1, sc[ct], 0, 0, 0);
        }

        // fixed-shift softmax: p = 2^s directly; per-lane partial row sums
        char* pls = (char*)&Ps[w][0];
        for (int ct = 0; ct < 4; ++ct)
            for (int r = 0; r < 4; ++r) {
                const float p = __builtin_amdgcn_exp2f(sc[ct][r]);
                lsum[r] += p;
                const int row = hi * 4 + r;
                *(short*)(pls + row * 128 + ((ct * 32 + lo * 2) ^ ((row & 7) << 4))) = f2bf(p);
            }

        short8 pf0 = *(const short8*)(pls + lo * 128 + ((hi * 16) ^ rsw));
        short8 pf1 = *(const short8*)(pls + lo * 128 + ((64 + hi * 16) ^ rsw));
        const char* vls = (const char*)&Vs[cb][0];
        for (int dt = 0; dt < 4; ++dt) {
            const int row = dt * 16 + lo;
            short8 vf0 = *(const short8*)(vls + row * 128 + ((hi * 16) ^ rsw));
            short8 vf1 = *(const short8*)(vls + row * 128 + ((64 + hi * 16) ^ rsw));
            oacc[dt] = __builtin_amdgcn_mfma_f32_16x16x32_bf16(pf0, vf0, oacc[dt], 0, 0, 0);
            oacc[dt] = __builtin_amdgcn_mfma_f32_16x16x32_bf16(pf1, vf1, oacc[dt], 0, 0, 0);
        }
        __syncthreads();
    }

    // deferred row-sum reduce over the 16 lo-lanes
    for (int r = 0; r < 4; ++r)
        for (int mk = 1; mk <= 8; mk <<= 1)
            lsum[r] += __shfl_xor(lsum[r], mk, 64);

    // epilogue: write attn output bf16 into [B,S,H] (head-merged)
    for (int r = 0; r < 4; ++r) {
        const int qg = qt * 64 + w * 16 + hi * 4 + r;
        const float inv = lsum[r] > 0.0f ? 1.0f / lsum[r] : 0.0f;
        for (int dt = 0; dt < 4; ++dt) {
            const int d = dt * 16 + lo;
            Ob[((long)b * SEQ + qg) * HDIM + h * 64 + d] = f2bf(oacc[dt][r] * inv);
        }
    }
}

// ---------------- host launch ----------------
extern "C" void kernel_launch(void* const* d_in, const int* in_sizes, int n_in,
                              void* d_out, int out_size, void* d_ws, size_t ws_size,
                              hipStream_t stream) {
    const float* q    = (const float*)d_in[0];
    const float* k    = (const float*)d_in[1];
    const float* v    = (const float*)d_in[2];
    const void*  mask = d_in[3];
    const float* rel  = (const float*)d_in[4];
    const float* Wq   = (const float*)d_in[5];
    const float* bq   = (const float*)d_in[6];
    const float* Wk   = (const float*)d_in[7];
    const float* bk   = (const float*)d_in[8];
    const float* Wv   = (const float*)d_in[9];
    const float* bv   = (const float*)d_in[10];
    const float* Wo   = (const float*)d_in[11];
    const float* bo   = (const float*)d_in[12];
    (void)in_sizes; (void)n_in; (void)out_size; (void)ws_size;

    char* ws = (char*)d_ws;
    size_t off = 0;
    auto alloc = [&](size_t bytes) {
        char* p = ws + off;
        off += (bytes + 255) & ~(size_t)255;
        return p;
    };
    const size_t xBytes = (size_t)MROWS * HDIM * 2;      // 8 MB bf16
    const size_t wBytes = (size_t)HDIM * HDIM * 2;       // 2 MB bf16
    const int    relPos = BATCH * 512 * 2048;            // float4 count
    const size_t relBytes = (size_t)relPos * 16;         // 32 MB f32

    // persistent region
    short* Qb  = (short*)alloc(xBytes);
    short* Kb  = (short*)alloc(xBytes);
    short* Vt  = (short*)alloc(xBytes);
    short* wob = (short*)alloc(wBytes);
    int*   flag = (int*)alloc(256);
    // pool: phase 1 = xq,xk,xv,wqb,wkb,wvb (30 MB); phase 2 = relm (32 MB)
    char* pool = (char*)alloc(relBytes);
    short* Ab  = (short*)alloc(xBytes);

    short* xq  = (short*)(pool);
    short* xk  = (short*)(pool + xBytes);
    short* xv  = (short*)(pool + 2 * xBytes);
    short* wqb = (short*)(pool + 3 * xBytes);
    short* wkb = (short*)(pool + 3 * xBytes + wBytes);
    short* wvb = (short*)(pool + 3 * xBytes + 2 * wBytes);
    float* relm = (float*)pool;

    const int n4x = MROWS * HDIM / 4, n4w = HDIM * HDIM / 4;
    cvt_qkv_kernel<<<1024, 256, 0, stream>>>(q, k, v, xq, xk, xv, n4x);
    cvt_w4_kernel<<<512, 256, 0, stream>>>(Wq, Wk, Wv, Wo, wqb, wkb, wvb, wob, n4w);
    detect_mask_kernel<<<1, 256, 0, stream>>>((const unsigned int*)mask, flag);

    qkv_gemm<<<768, 256, 0, stream>>>(xq, xk, xv, wqb, wkb, wvb,
                                      bq, bk, bv, Qb, Kb, Vt);

    // pool is dead for x/w now; build relm over it
    fuse_rel_kernel<<<2048, 256, 0, stream>>>(rel, mask, flag, relm, relPos);

    attn_fwd<<<1024, 256, 0, stream>>>(Qb, Kb, Vt, relm, Ab);

    out_gemm<<<256, 256, 0, stream>>>(Ab, wob, bo, (float*)d_out);
}

// Round 6
// 168.909 us; speedup vs baseline: 2.1407x; 1.0992x over previous
//
#include <hip/hip_runtime.h>
#include <hip/hip_bf16.h>

// Problem constants
constexpr int BATCH = 2, SEQ = 2048, HDIM = 1024, NHEADS = 16, HEADD = 64;
constexpr int MROWS = BATCH * SEQ;            // 4096
// fold attention scale and exp->exp2 conversion: c = 0.125 / ln(2)
constexpr float QSCALE = 0.18033688011112042f;

typedef short short8  __attribute__((ext_vector_type(8)));
typedef float f32x4   __attribute__((ext_vector_type(4)));
typedef float f32x16  __attribute__((ext_vector_type(16)));
typedef int   int4v   __attribute__((ext_vector_type(4)));
typedef unsigned short ushort4v __attribute__((ext_vector_type(4)));

static __device__ __forceinline__ short f2bf(float f) {
    __hip_bfloat16 h = __float2bfloat16(f);
    return *reinterpret_cast<short*>(&h);
}

static __device__ __forceinline__ int cvt_pk_bf16(float a, float b) {
    int r;
    asm("v_cvt_pk_bf16_f32 %0, %1, %2" : "=v"(r) : "v"(a), "v"(b));
    return r;
}

static __device__ __forceinline__ float bfbits2f(unsigned short u) {
    return __builtin_bit_cast(float, (unsigned int)u << 16);
}

static __device__ __forceinline__ void gload_lds16(const void* g, void* l) {
    __builtin_amdgcn_global_load_lds(
        (const __attribute__((address_space(1))) unsigned int*)g,
        (__attribute__((address_space(3))) unsigned int*)l, 16, 0, 0);
}

// ---------------- conversions: f32 -> bf16 (x4 vectorized, fused) ----------------
__global__ void cvt_qkv_kernel(const float* __restrict__ q, const float* __restrict__ k,
                               const float* __restrict__ v, short* __restrict__ xq,
                               short* __restrict__ xk, short* __restrict__ xv, int n4) {
    int i = blockIdx.x * blockDim.x + threadIdx.x;
    const int stride = gridDim.x * blockDim.x;
    for (; i < 3 * n4; i += stride) {
        const float* in; short* out; int j = i;
        if (j >= 2 * n4)      { in = v; out = xv; j -= 2 * n4; }
        else if (j >= n4)     { in = k; out = xk; j -= n4; }
        else                  { in = q; out = xq; }
        const float4 val = reinterpret_cast<const float4*>(in)[j];
        short4 o;
        o.x = f2bf(val.x); o.y = f2bf(val.y); o.z = f2bf(val.z); o.w = f2bf(val.w);
        reinterpret_cast<short4*>(out)[j] = o;
    }
}

__global__ void cvt_w4_kernel(const float* __restrict__ w0, const float* __restrict__ w1,
                              const float* __restrict__ w2, const float* __restrict__ w3,
                              short* __restrict__ o0, short* __restrict__ o1,
                              short* __restrict__ o2, short* __restrict__ o3, int n4) {
    int i = blockIdx.x * blockDim.x + threadIdx.x;
    const int stride = gridDim.x * blockDim.x;
    for (; i < 4 * n4; i += stride) {
        const float* in; short* out; int j = i;
        if (j >= 3 * n4)      { in = w3; out = o3; j -= 3 * n4; }
        else if (j >= 2 * n4) { in = w2; out = o2; j -= 2 * n4; }
        else if (j >= n4)     { in = w1; out = o1; j -= n4; }
        else                  { in = w0; out = o0; }
        const float4 val = reinterpret_cast<const float4*>(in)[j];
        short4 o;
        o.x = f2bf(val.x); o.y = f2bf(val.y); o.z = f2bf(val.z); o.w = f2bf(val.w);
        reinterpret_cast<short4*>(out)[j] = o;
    }
}

// ---------------- mask dtype probe ----------------
__global__ void detect_mask_kernel(const unsigned int* __restrict__ m, int* flag) {
    const int tid = threadIdx.x;
    int gt1 = 0, isf = 0;
    for (int i = 0; i < 4; ++i) {
        unsigned int wv = m[tid + 256 * i];
        if (wv > 1u) gt1 = 1;
        if (wv == 0x3F800000u) isf = 1;
    }
    __shared__ int s_gt1, s_isf;
    if (tid == 0) { s_gt1 = 0; s_isf = 0; }
    __syncthreads();
    if (gt1) atomicOr(&s_gt1, 1);
    if (isf) atomicOr(&s_isf, 1);
    __syncthreads();
    if (tid == 0) flag[0] = s_gt1 ? (s_isf ? 2 : 1) : 0;
}

// ---------------- fuse mask + rel -> rT: transposed bf16 planes ----------------
// rT short4-index [(b*512 + kv/4)*2048 + q], component j = kv%4:
//   rT[...][j] = mask[b][q][kv] ? bf16(rel[b][q][kv] * QSCALE) : bf16(-1e30f)
// thread i -> (b, kv16, q), q fastest (coalesced writes; full-line reads)
__global__ void fuse_rel_kernel(const float* __restrict__ rel, const void* __restrict__ mask,
                                const int* __restrict__ flag, short* __restrict__ rT,
                                int nThr) {   // nThr = BATCH*128*2048
    const int f = flag[0];
    int i = blockIdx.x * blockDim.x + threadIdx.x;
    const int stride = gridDim.x * blockDim.x;
    for (; i < nThr; i += stride) {
        const int q    = i & 2047;
        const int kv16 = (i >> 11) & 127;
        const int b    = i >> 18;
        const long base = ((long)(b * 2048 + q)) * 2048 + kv16 * 16;  // element index
        float4 rv[4];
        #pragma unroll
        for (int g = 0; g < 4; ++g)
            rv[g] = *reinterpret_cast<const float4*>(rel + base + 4 * g);
        bool mk[16];
        if (f == 1) {
            const unsigned int* mp = (const unsigned int*)((const unsigned char*)mask + base);
            #pragma unroll
            for (int wd = 0; wd < 4; ++wd) {
                const unsigned int mw = mp[wd];
                #pragma unroll
                for (int s = 0; s < 4; ++s) mk[wd * 4 + s] = ((mw >> (8 * s)) & 0xffu) != 0;
            }
        } else if (f == 0) {
            const int* mp = (const int*)mask + base;
            #pragma unroll
            for (int j = 0; j < 16; ++j) mk[j] = mp[j] != 0;
        } else {
            const float* mp = (const float*)mask + base;
            #pragma unroll
            for (int j = 0; j < 16; ++j) mk[j] = mp[j] != 0.0f;
        }
        const float* rp = reinterpret_cast<const float*>(&rv[0]);
        #pragma unroll
        for (int g = 0; g < 4; ++g) {
            short4 o;
            short* op = reinterpret_cast<short*>(&o);
            #pragma unroll
            for (int j = 0; j < 4; ++j) {
                const int idx = 4 * g + j;
                op[j] = f2bf(mk[idx] ? rp[idx] * QSCALE : -1e30f);
            }
            *reinterpret_cast<short4*>(rT + (((long)(b * 512 + kv16 * 4 + g)) * 2048 + q) * 4) = o;
        }
    }
}

// ================= GEMM core (128x128 tile, BK=64, 2-phase) =================
template<typename EPI>
static __device__ __forceinline__
void gemm_core(const short* A, const short* Bw, int K, int m0, int n0, EPI epi) {
    __shared__ short As[128 * 64];
    __shared__ short Bs[128 * 64];
    const int tid  = threadIdx.x;
    const int lane = tid & 63;
    const int w    = tid >> 6;
    const int lo   = lane & 15, hi = lane >> 4;
    const int wm   = w >> 1, wn = w & 1;

    f32x4 acc[4][4] = {};

    const int arow = tid >> 3;
    const int acol = (tid & 7) * 8;
    const long aBase = (long)(m0 + arow) * K + acol;
    const long bBase = (long)(n0 + arow) * K + acol;

    for (int k0 = 0; k0 < K; k0 += 64) {
        for (int i = 0; i < 4; ++i) {
            gload_lds16(A  + aBase + (long)i * 32 * K + k0, (char*)As + i * 4096 + tid * 16);
            gload_lds16(Bw + bBase + (long)i * 32 * K + k0, (char*)Bs + i * 4096 + tid * 16);
        }
        __syncthreads();
        for (int ks = 0; ks < 2; ++ks) {
            short8 af[4], bf[4];
            const int koff = ks * 32 + hi * 8;
            for (int fm = 0; fm < 4; ++fm)
                af[fm] = *reinterpret_cast<const short8*>(&As[(wm * 64 + fm * 16 + lo) * 64 + koff]);
            for (int fn = 0; fn < 4; ++fn)
                bf[fn] = *reinterpret_cast<const short8*>(&Bs[(wn * 64 + fn * 16 + lo) * 64 + koff]);
            for (int fm = 0; fm < 4; ++fm)
                for (int fn = 0; fn < 4; ++fn)
                    acc[fm][fn] = __builtin_amdgcn_mfma_f32_16x16x32_bf16(
                        af[fm], bf[fn], acc[fm][fn], 0, 0, 0);
        }
        __syncthreads();
    }

    for (int fm = 0; fm < 4; ++fm)
        for (int fn = 0; fn < 4; ++fn) {
            const int n = n0 + wn * 64 + fn * 16 + lo;
            const int mB = m0 + wm * 64 + fm * 16 + hi * 4;
            for (int r = 0; r < 4; ++r) epi(mB + r, n, acc[fm][fn][r]);
        }
}

// merged Q/K/V projection: grid = 3*256 blocks; which = blockIdx.x>>8
__global__ __launch_bounds__(256, 2)
void qkv_gemm(const short* xq, const short* xk, const short* xv,
              const short* wq, const short* wk, const short* wv,
              const float* bq, const float* bk, const float* bv,
              short* Qb, short* Kb, short* Vt) {
    const int which = blockIdx.x >> 8;
    const int bid   = blockIdx.x & 255;
    const int m0 = (bid >> 3) << 7;
    const int n0 = (bid & 7) << 7;
    const short* A    = which == 0 ? xq : which == 1 ? xk : xv;
    const short* W    = which == 0 ? wq : which == 1 ? wk : wv;
    const float* bias = which == 0 ? bq : which == 1 ? bk : bv;
    short* C          = which == 0 ? Qb : which == 1 ? Kb : Vt;
    const float scale = which == 0 ? QSCALE : 1.0f;
    gemm_core(A, W, HDIM, m0, n0, [&](int m, int n, float v) {
        v = (v + bias[n]) * scale;
        const int b = m >> 11, s = m & (SEQ - 1);
        const int h = n >> 6, d = n & 63;
        long idx;
        if (which != 2) idx = (((long)(b * NHEADS + h)) * SEQ + s) * HEADD + d;
        else            idx = (((long)(b * NHEADS + h)) * HEADD + d) * SEQ + s;
        C[idx] = f2bf(v);
    });
}

// final output projection: f32 out [M,N]
__global__ __launch_bounds__(256, 2)
void out_gemm(const short* A, const short* W, const float* bias, float* Cout) {
    const int bid = blockIdx.x;
    const int m0 = (bid >> 3) << 7;
    const int n0 = (bid & 7) << 7;
    gemm_core(A, W, HDIM, m0, n0, [&](int m, int n, float v) {
        Cout[(long)m * HDIM + n] = v + bias[n];
    });
}

// ---------------- flash attention (32x32 swapped, P in-register) ----------------
// grid 512 (XCD-chunked); 4 waves x 32 q-rows = QBLK 128; KV tiles of 64.
// QK^T computed swapped: sc = mfma(K, Q) -> lane owns one q column.
// P redistributed to PV A-fragments via cvt_pk_bf16 + permlane32_swap (no LDS).
__global__ __launch_bounds__(256, 2)
void attn_fwd(const short* __restrict__ Qb, const short* __restrict__ Kb,
              const short* __restrict__ Vtb, const short* __restrict__ rT,
              short* __restrict__ Ob) {
    __shared__ short Ks[2][64 * 64];
    __shared__ short Vs[2][64 * 64];
    const int tid  = threadIdx.x;
    const int lane = tid & 63;
    const int wq   = tid >> 6;
    const int l31  = lane & 31, hi2 = lane >> 5;
    // XCD-chunked swizzle: 512 blocks, 8 XCDs, 64 contiguous wgs each
    const int wg = ((blockIdx.x & 7) << 6) + (blockIdx.x >> 3);
    const int qt = wg & 15, h = (wg >> 4) & 15, b = wg >> 8;
    const int bh = b * NHEADS + h;
    const int q0 = qt * 128 + wq * 32 + l31;     // this lane's q row

    // Q as B-fragments: qf[s] = Q[q0][s*16 + hi2*8 .. +7]
    short8 qf[4];
    {
        const short* qp = Qb + ((long)bh * SEQ + q0) * HEADD + hi2 * 8;
        #pragma unroll
        for (int s = 0; s < 4; ++s)
            qf[s] = *reinterpret_cast<const short8*>(qp + s * 16);
    }

    float lsum = 0.0f;
    f32x16 oacc0 = {}, oacc1 = {};

    // K/V staging (pre-swizzled global source -> linear LDS dest)
    const int srow  = tid >> 3;
    const int scolb = (tid & 7) * 16;
    const int scolK = scolb ^ ((srow & 7) << 4);
    const char* KbB = (const char*)Kb + ((long)bh * SEQ + srow) * 128 + scolK;
    const char* VbB = (const char*)Vtb + ((long)bh * HEADD + srow) * ((long)SEQ * 2) + scolK;

    auto stage = [&](int buf, int kt) {
        #pragma unroll
        for (int i = 0; i < 2; ++i) {
            gload_lds16(KbB + ((long)kt * 64 + i * 32) * 128,
                        (char*)&Ks[buf][0] + i * 4096 + tid * 16);
            gload_lds16(VbB + (long)i * 32 * (SEQ * 2) + (long)kt * 128,
                        (char*)&Vs[buf][0] + i * 4096 + tid * 16);
        }
    };

    // bias C-init prefetch (bf16x4 planes)
    ushort4v rbuf[8];
    auto loadRel = [&](int kt) {
        #pragma unroll
        for (int t = 0; t < 2; ++t)
            #pragma unroll
            for (int g = 0; g < 4; ++g) {
                const int p4 = kt * 16 + t * 8 + 2 * g + hi2;
                rbuf[t * 4 + g] = *reinterpret_cast<const ushort4v*>(
                    rT + (((long)(b * 512 + p4)) * 2048 + q0) * 4);
            }
    };

    stage(0, 0);
    loadRel(0);
    __syncthreads();

    const int rsw = (l31 & 7) << 4;

    for (int kt = 0; kt < SEQ / 64; ++kt) {
        const int cb = kt & 1;
        if (kt < SEQ / 64 - 1) stage(cb ^ 1, kt + 1);

        // C-init from prefetched bias, then prefetch next
        f32x16 sc[2];
        #pragma unroll
        for (int t = 0; t < 2; ++t)
            #pragma unroll
            for (int g = 0; g < 4; ++g)
                #pragma unroll
                for (int j = 0; j < 4; ++j)
                    sc[t][4 * g + j] = bfbits2f(rbuf[t * 4 + g][j]);
        loadRel(kt < SEQ / 64 - 1 ? kt + 1 : 0);

        // QK^T (swapped): sc[t] = K_tile^T-rows x Q-cols; D row=kv, col=q
        const char* kls = (const char*)&Ks[cb][0];
        __builtin_amdgcn_s_setprio(1);
        #pragma unroll
        for (int t = 0; t < 2; ++t) {
            const char* kr = kls + (t * 32 + l31) * 128;
            #pragma unroll
            for (int s = 0; s < 4; ++s) {
                short8 kf = *reinterpret_cast<const short8*>(kr + ((s * 32 + hi2 * 16) ^ rsw));
                sc[t] = __builtin_amdgcn_mfma_f32_32x32x16_bf16(kf, qf[s], sc[t], 0, 0, 0);
            }
        }
        __builtin_amdgcn_s_setprio(0);

        // softmax (fixed shift): p = 2^sc, lane-local row partial sums;
        // pack to bf16 pairs and redistribute into PV A-fragments.
        // permlane32_swap(lowkv, highkv): ret[0] = both lo-halves (lo-kv word),
        // ret[1] = both hi-halves (hi-kv word)  [vdst.hi <-> vsrc.lo semantics]
        int pa[4][4];
        #pragma unroll
        for (int t = 0; t < 2; ++t) {
            int X[8];
            #pragma unroll
            for (int i2 = 0; i2 < 8; ++i2) {
                const float p0 = __builtin_amdgcn_exp2f(sc[t][2 * i2]);
                const float p1 = __builtin_amdgcn_exp2f(sc[t][2 * i2 + 1]);
                lsum += p0 + p1;
                X[i2] = cvt_pk_bf16(p0, p1);
            }
            #pragma unroll
            for (int u = 0; u < 2; ++u) {
                auto r0 = __builtin_amdgcn_permlane32_swap(X[4 * u + 0], X[4 * u + 2], false, false);
                auto r1 = __builtin_amdgcn_permlane32_swap(X[4 * u + 1], X[4 * u + 3], false, false);
                pa[2 * t + u][0] = (int)r0[0];
                pa[2 * t + u][1] = (int)r1[0];
                pa[2 * t + u][2] = (int)r0[1];
                pa[2 * t + u][3] = (int)r1[1];
            }
        }

        // PV: oacc[dt] += P(A) x V(B); B col=d, k=kv
        const char* vls = (const char*)&Vs[cb][0];
        __builtin_amdgcn_s_setprio(1);
        #pragma unroll
        for (int dt = 0; dt < 2; ++dt) {
            const char* vr = vls + (dt * 32 + l31) * 128;
            #pragma unroll
            for (int s = 0; s < 4; ++s) {
                short8 vf = *reinterpret_cast<const short8*>(vr + ((s * 32 + hi2 * 16) ^ rsw));
                int4v pw = { pa[s][0], pa[s][1], pa[s][2], pa[s][3] };
                if (dt == 0)
                    oacc0 = __builtin_amdgcn_mfma_f32_32x32x16_bf16(
                        __builtin_bit_cast(short8, pw), vf, oacc0, 0, 0, 0);
                else
                    oacc1 = __builtin_amdgcn_mfma_f32_32x32x16_bf16(
                        __builtin_bit_cast(short8, pw), vf, oacc1, 0, 0, 0);
            }
        }
        __builtin_amdgcn_s_setprio(0);
        __syncthreads();
    }

    // row-sum finish: halves hold complementary kv ranges for the same q
    lsum += __shfl_xor(lsum, 32, 64);
    const float inv = lsum > 0.0f ? 1.0f / lsum : 0.0f;

    // epilogue: D row=q=(r&3)+8*(r>>2)+4*hi2, col=d=dt*32+l31
    #pragma unroll
    for (int r = 0; r < 16; ++r) {
        const int qloc = (r & 3) + 8 * (r >> 2) + 4 * hi2;
        const float invr = __shfl(inv, qloc, 64);
        const int qg = qt * 128 + wq * 32 + qloc;
        const long obase = ((long)b * SEQ + qg) * HDIM + h * 64 + l31;
        Ob[obase]      = f2bf(oacc0[r] * invr);
        Ob[obase + 32] = f2bf(oacc1[r] * invr);
    }
}

// ---------------- host launch ----------------
extern "C" void kernel_launch(void* const* d_in, const int* in_sizes, int n_in,
                              void* d_out, int out_size, void* d_ws, size_t ws_size,
                              hipStream_t stream) {
    const float* q    = (const float*)d_in[0];
    const float* k    = (const float*)d_in[1];
    const float* v    = (const float*)d_in[2];
    const void*  mask = d_in[3];
    const float* rel  = (const float*)d_in[4];
    const float* Wq   = (const float*)d_in[5];
    const float* bq   = (const float*)d_in[6];
    const float* Wk   = (const float*)d_in[7];
    const float* bk   = (const float*)d_in[8];
    const float* Wv   = (const float*)d_in[9];
    const float* bv   = (const float*)d_in[10];
    const float* Wo   = (const float*)d_in[11];
    const float* bo   = (const float*)d_in[12];
    (void)in_sizes; (void)n_in; (void)out_size; (void)ws_size;

    char* ws = (char*)d_ws;
    size_t off = 0;
    auto alloc = [&](size_t bytes) {
        char* p = ws + off;
        off += (bytes + 255) & ~(size_t)255;
        return p;
    };
    const size_t xBytes = (size_t)MROWS * HDIM * 2;      // 8 MB bf16
    const size_t wBytes = (size_t)HDIM * HDIM * 2;       // 2 MB bf16
    const size_t poolBytes = 3 * xBytes + 3 * wBytes;    // 30 MB (>= rT's 16 MB)

    // persistent region
    short* Qb  = (short*)alloc(xBytes);
    short* Kb  = (short*)alloc(xBytes);
    short* Vt  = (short*)alloc(xBytes);
    short* wob = (short*)alloc(wBytes);
    int*   flag = (int*)alloc(256);
    // pool: phase 1 = xq,xk,xv,wqb,wkb,wvb; phase 2 = rT (16 MB)
    char* pool = (char*)alloc(poolBytes);
    short* Ab  = (short*)alloc(xBytes);

    short* xq  = (short*)(pool);
    short* xk  = (short*)(pool + xBytes);
    short* xv  = (short*)(pool + 2 * xBytes);
    short* wqb = (short*)(pool + 3 * xBytes);
    short* wkb = (short*)(pool + 3 * xBytes + wBytes);
    short* wvb = (short*)(pool + 3 * xBytes + 2 * wBytes);
    short* rT  = (short*)(pool);

    const int n4x = MROWS * HDIM / 4, n4w = HDIM * HDIM / 4;
    cvt_qkv_kernel<<<1024, 256, 0, stream>>>(q, k, v, xq, xk, xv, n4x);
    cvt_w4_kernel<<<512, 256, 0, stream>>>(Wq, Wk, Wv, Wo, wqb, wkb, wvb, wob, n4w);
    detect_mask_kernel<<<1, 256, 0, stream>>>((const unsigned int*)mask, flag);

    qkv_gemm<<<768, 256, 0, stream>>>(xq, xk, xv, wqb, wkb, wvb,
                                      bq, bk, bv, Qb, Kb, Vt);

    // pool is dead for x/w now; build rT over it
    const int relThr = BATCH * 128 * 2048;
    fuse_rel_kernel<<<2048, 256, 0, stream>>>(rel, mask, flag, rT, relThr);

    attn_fwd<<<512, 256, 0, stream>>>(Qb, Kb, Vt, rT, Ab);

    out_gemm<<<256, 256, 0, stream>>>(Ab, wob, bo, (float*)d_out);
}